// Round 8
// baseline (260.905 us; speedup 1.0000x reference)
//
#include <hip/hip_runtime.h>

typedef unsigned long long u64;
typedef unsigned int u32;
typedef int  v4i __attribute__((ext_vector_type(4)));
typedef unsigned int v4u __attribute__((ext_vector_type(4)));

#define TBL_BITS 18
#define TBL_SIZE (1u << TBL_BITS)
#define TBL_MASK (TBL_SIZE - 1u)
#define EMPTY_KEY 0xFFFFFFFFFFFFFFFFull

#define BK_BITS 9                 // 512-node buckets
#define BK_SZ   512
#define MAXNB   256               // max coarse buckets in fast path
#define NBLK    512               // partition blocks (2 workgroups/CU)
#define NSUB    8                 // nb sub-blocks per bucket

__device__ __forceinline__ u64 splitmix64(u64 z) {
    z = z + 0x9E3779B97F4A7C15ull;
    z = (z ^ (z >> 30)) * 0xBF58476D1CE4E5B9ull;
    z = (z ^ (z >> 27)) * 0x94D049BB133111EBull;
    return z ^ (z >> 31);
}

__device__ __forceinline__ v4i nt_load4(const int* p) {
    return __builtin_nontemporal_load((const v4i*)p);
}
__device__ __forceinline__ v4u nt_loadu4(const u32* p) {
    return __builtin_nontemporal_load((const v4u*)p);
}

// colors0 = argmax over 64 features per node (one wave per row); writes output
// column 0, h = splitmix64(color+1), and offsets[0] = 0.
__global__ void argmax_kernel(const float* __restrict__ x, u64* __restrict__ h,
                              int* __restrict__ out, u32* __restrict__ offsets, int n) {
    if (blockIdx.x == 0 && threadIdx.x == 0) offsets[0] = 0u;
    int wave = (int)((blockIdx.x * (u32)blockDim.x + threadIdx.x) >> 6);
    int lane = threadIdx.x & 63;
    if (wave >= n) return;
    float v = x[(size_t)wave * 64 + lane];
    int idx = lane;
    #pragma unroll
    for (int off = 32; off >= 1; off >>= 1) {
        float ov = __shfl_xor(v, off);
        int   oi = __shfl_xor(idx, off);
        if (ov > v || (ov == v && oi < idx)) { v = ov; idx = oi; }
    }
    if (lane == 0) {
        h[wave] = splitmix64((u64)idx + 1ull);
        out[(size_t)wave * 4 + 0] = idx;
    }
}

// ---------------- fast path: one-time edge partition ----------------

// Per-block LDS histogram of dst buckets -> cnt[bucket*NBLK + blk]. int4 loads.
__global__ __launch_bounds__(1024) void count_part(const int* __restrict__ dst,
                                                   u32* __restrict__ cnt, int m, int nbuck) {
    __shared__ u32 hist[MAXNB];
    int t = threadIdx.x, b = blockIdx.x;
    for (int i = t; i < nbuck; i += 1024) hist[i] = 0u;
    __syncthreads();
    int mv = m >> 2;
    int perv = (mv + NBLK - 1) / NBLK;
    int lo = b * perv, hi = lo + perv; if (hi > mv) hi = mv;
    for (int i = lo + t; i < hi; i += 1024) {
        v4i v = nt_load4(dst + 4 * (size_t)i);
        atomicAdd(&hist[((u32)v.x) >> BK_BITS], 1u);
        atomicAdd(&hist[((u32)v.y) >> BK_BITS], 1u);
        atomicAdd(&hist[((u32)v.z) >> BK_BITS], 1u);
        atomicAdd(&hist[((u32)v.w) >> BK_BITS], 1u);
    }
    if (b == 0 && t == 0)
        for (int e = mv * 4; e < m; ++e) atomicAdd(&hist[((u32)dst[e]) >> BK_BITS], 1u);
    __syncthreads();
    for (int i = t; i < nbuck; i += 1024) cnt[i * NBLK + b] = hist[i];
}

// In-place exclusive scan of each bucket's NBLK counters; emit bucket totals.
__global__ __launch_bounds__(512) void scan_bucket(u32* __restrict__ cnt,
                                                   u32* __restrict__ total, int nbuck) {
    int b = blockIdx.x, t = threadIdx.x;          // 512 threads == NBLK
    u32 v = cnt[b * NBLK + t];
    int lane = t & 63, w = t >> 6;                 // 8 waves
    int x = (int)v;
    #pragma unroll
    for (int o = 1; o < 64; o <<= 1) {
        int y = __shfl_up(x, o);
        if (lane >= o) x += y;
    }
    __shared__ u32 ws[8];
    if (lane == 63) ws[w] = (u32)x;
    __syncthreads();
    u32 woff = 0;
    for (int ww = 0; ww < w; ++ww) woff += ws[ww];
    u32 incl = woff + (u32)x;
    cnt[b * NBLK + t] = incl - v;                 // exclusive, in place
    if (t == NBLK - 1) total[b] = incl;
}

// Exclusive scan of bucket totals (padded to 64-entry alignment).
__global__ void scan_bases(const u32* __restrict__ total, u32* __restrict__ bases, int nbuck) {
    __shared__ u32 A[256], B[256];
    int t = threadIdx.x;
    u32 pt = (t < nbuck) ? ((total[t] + 63u) & ~63u) : 0u;
    A[t] = pt; __syncthreads();
    u32 *cur = A, *nxt = B;
    for (int o = 1; o < 256; o <<= 1) {
        u32 y = cur[t] + ((t >= o) ? cur[t - o] : 0u);
        nxt[t] = y; __syncthreads();
        u32* tmp = cur; cur = nxt; nxt = tmp;
    }
    if (t < nbuck) bases[t] = cur[t] - pt;
}

// Scatter edges into bucket regions: packed = (src<<9)|(dst&511). Position
// order within a region is nondeterministic, but downstream sums are
// commutative -> final output exact/deterministic.
__global__ __launch_bounds__(1024) void scatter_part(const int* __restrict__ src,
                                                     const int* __restrict__ dst,
                                                     const u32* __restrict__ cnt,
                                                     const u32* __restrict__ bases,
                                                     u32* __restrict__ packed, int m, int nbuck) {
    __shared__ u32 pos[MAXNB];
    int t = threadIdx.x, b = blockIdx.x;
    for (int i = t; i < nbuck; i += 1024) pos[i] = bases[i] + cnt[i * NBLK + b];
    __syncthreads();
    int mv = m >> 2;
    int perv = (mv + NBLK - 1) / NBLK;
    int lo = b * perv, hi = lo + perv; if (hi > mv) hi = mv;
    for (int i = lo + t; i < hi; i += 1024) {
        v4i dv = nt_load4(dst + 4 * (size_t)i);
        v4i sv = nt_load4(src + 4 * (size_t)i);
        u32 d0 = (u32)dv.x, d1 = (u32)dv.y, d2 = (u32)dv.z, d3 = (u32)dv.w;
        u32 p0 = atomicAdd(&pos[d0 >> BK_BITS], 1u);
        packed[p0] = ((u32)sv.x << BK_BITS) | (d0 & (BK_SZ - 1u));
        u32 p1 = atomicAdd(&pos[d1 >> BK_BITS], 1u);
        packed[p1] = ((u32)sv.y << BK_BITS) | (d1 & (BK_SZ - 1u));
        u32 p2 = atomicAdd(&pos[d2 >> BK_BITS], 1u);
        packed[p2] = ((u32)sv.z << BK_BITS) | (d2 & (BK_SZ - 1u));
        u32 p3 = atomicAdd(&pos[d3 >> BK_BITS], 1u);
        packed[p3] = ((u32)sv.w << BK_BITS) | (d3 & (BK_SZ - 1u));
    }
    if (b == 0 && t == 0) {
        for (int e = mv * 4; e < m; ++e) {
            u32 d = (u32)dst[e];
            u32 p = atomicAdd(&pos[d >> BK_BITS], 1u);
            packed[p] = ((u32)src[e] << BK_BITS) | (d & (BK_SZ - 1u));
        }
    }
}

// Blocks [0, nbuck*NSUB): sub-block s of bucket b accumulates its 1/NSUB of
// the bucket's edges into 512 u64 LDS accumulators, then OVERWRITES its slice
// of partial array nb8[s] (no global atomics, no pre-clear needed).
// Blocks [nbuck*NSUB, +256): clear the hash table.
__global__ __launch_bounds__(256) void nb_kernel(const u32* __restrict__ packed,
                                                 const u32* __restrict__ bases,
                                                 const u32* __restrict__ total,
                                                 const u64* __restrict__ h,
                                                 u64* __restrict__ nb8, size_t nstride,
                                                 u64* __restrict__ keys,
                                                 u32* __restrict__ vals, int nbuck) {
    int b = blockIdx.x, t = threadIdx.x;
    if (b >= nbuck * NSUB) {
        int base = (b - nbuck * NSUB) * 1024;
        for (int k = t; k < 1024; k += 256) { keys[base + k] = EMPTY_KEY; vals[base + k] = 0xFFFFFFFFu; }
        return;
    }
    int bucket = b >> 3, sub = b & 7;
    __shared__ u64 acc[BK_SZ];
    acc[t] = 0ull; acc[t + 256] = 0ull;
    __syncthreads();
    u32 lo = bases[bucket];                        // 64-edge aligned
    u32 len = total[bucket];
    u32 q0 = ((len * (u32)sub) >> 3) & ~3u;
    u32 q1 = (sub == 7) ? len : (((len * (u32)(sub + 1)) >> 3) & ~3u);
    u32 nv4 = (q1 - q0) >> 2;
    const u32* pbase = packed + lo + q0;
    for (u32 i = (u32)t; i < nv4; i += 256) {
        v4u v = nt_loadu4(pbase + 4 * (size_t)i);
        atomicAdd(&acc[v.x & (BK_SZ - 1u)], h[v.x >> BK_BITS]);
        atomicAdd(&acc[v.y & (BK_SZ - 1u)], h[v.y >> BK_BITS]);
        atomicAdd(&acc[v.z & (BK_SZ - 1u)], h[v.z >> BK_BITS]);
        atomicAdd(&acc[v.w & (BK_SZ - 1u)], h[v.w >> BK_BITS]);
    }
    for (u32 e = q0 + nv4 * 4 + (u32)t; e < q1; e += 256) {
        u32 v = packed[lo + e];
        atomicAdd(&acc[v & (BK_SZ - 1u)], h[v >> BK_BITS]);
    }
    __syncthreads();
    u64* dstp = nb8 + (size_t)sub * nstride + ((size_t)bucket << BK_BITS);
    dstp[t] = acc[t];
    dstp[t + 256] = acc[t + 256];
}

// ---------------- per-iteration relabel chain ----------------

// sig = splitmix64(h*FNV + sum of NSUB nb partials); read-before-CAS insert;
// first occurrence via atomicMin (order-independent). Slots are write-once
// EMPTY->key, so a stale plain read yields EMPTY or the final key -> safe.
__global__ void sig_kernel8(const u64* __restrict__ h, const u64* __restrict__ nb8,
                            size_t nstride, u32* __restrict__ slotarr,
                            u64* __restrict__ keys, u32* __restrict__ vals, int n) {
    int i = blockIdx.x * blockDim.x + threadIdx.x;
    if (i >= n) return;
    u64 nbv = 0;
    #pragma unroll
    for (int s = 0; s < NSUB; ++s) nbv += nb8[(size_t)s * nstride + i];
    u64 sg = splitmix64(h[i] * 0x100000001B3ull + nbv);
    u32 slot = (u32)sg & TBL_MASK;
    while (true) {
        u64 k = keys[slot];
        if (k == sg) break;
        if (k == EMPTY_KEY) {
            u64 prev = atomicCAS(&keys[slot], (u64)EMPTY_KEY, sg);
            if (prev == EMPTY_KEY || prev == sg) break;
        }
        slot = (slot + 1u) & TBL_MASK;
    }
    atomicMin(&vals[slot], (u32)i);
    slotarr[i] = slot;
}

__global__ void sig_kernel1(const u64* __restrict__ h, const u64* __restrict__ nb,
                            u32* __restrict__ slotarr, u64* __restrict__ keys,
                            u32* __restrict__ vals, int n) {
    int i = blockIdx.x * blockDim.x + threadIdx.x;
    if (i >= n) return;
    u64 sg = splitmix64(h[i] * 0x100000001B3ull + nb[i]);
    u32 slot = (u32)sg & TBL_MASK;
    while (true) {
        u64 k = keys[slot];
        if (k == sg) break;
        if (k == EMPTY_KEY) {
            u64 prev = atomicCAS(&keys[slot], (u64)EMPTY_KEY, sg);
            if (prev == EMPTY_KEY || prev == sg) break;
        }
        slot = (slot + 1u) & TBL_MASK;
    }
    atomicMin(&vals[slot], (u32)i);
    slotarr[i] = slot;
}

// f[i] = first-occurrence index; per-256-chunk exclusive rank; chunk totals.
__global__ void count_rank(const u32* __restrict__ slotarr, const u32* __restrict__ vals,
                           u32* __restrict__ f, u32* __restrict__ lrank,
                           u32* __restrict__ partials, int n) {
    int b = blockIdx.x, t = threadIdx.x;
    int i = b * 256 + t;
    u32 isf = 0, fi = 0;
    if (i < n) {
        fi = vals[slotarr[i]];
        f[i] = fi;
        isf = (fi == (u32)i) ? 1u : 0u;
    }
    __shared__ u32 wsum[4];
    u32 lane = t & 63, wv = (u32)t >> 6;
    int x = (int)isf;
    #pragma unroll
    for (int o = 1; o < 64; o <<= 1) {
        int y = __shfl_up(x, o);
        if (lane >= (u32)o) x += y;
    }
    if (lane == 63) wsum[wv] = (u32)x;
    __syncthreads();
    u32 woff = 0;
    for (u32 w = 0; w < wv; ++w) woff += wsum[w];
    if (i < n) lrank[i] = woff + (u32)x - isf;
    if (t == 255) partials[b] = woff + (u32)x;
}

// Fused: every block redundantly block-scans the per-chunk partials in LDS,
// then relabels 512 nodes: color = offset + pp[chunk(f)] + lrank[f].
// Block 0 also advances the persistent color counter.
__global__ __launch_bounds__(512) void relabel_fused(const u32* __restrict__ f,
                                                     const u32* __restrict__ lrank,
                                                     const u32* __restrict__ partials,
                                                     u32* __restrict__ offsets, int iter,
                                                     u64* __restrict__ h, int* __restrict__ out,
                                                     int n, int npb) {
    __shared__ u32 pp[512];
    __shared__ u32 ws[8];
    int t = threadIdx.x;
    u32 v = (t < npb) ? partials[t] : 0u;
    int lane = t & 63, w = t >> 6;
    int x = (int)v;
    #pragma unroll
    for (int o = 1; o < 64; o <<= 1) {
        int y = __shfl_up(x, o);
        if (lane >= o) x += y;
    }
    if (lane == 63) ws[w] = (u32)x;
    __syncthreads();
    u32 woff = 0;
    for (int ww = 0; ww < w; ++ww) woff += ws[ww];
    u32 incl = woff + (u32)x;
    pp[t] = incl - v;                       // exclusive prefix
    if (blockIdx.x == 0 && t == 511) offsets[iter + 1] = offsets[iter] + incl;
    __syncthreads();
    int i = blockIdx.x * 512 + t;
    if (i >= n) return;
    u32 j = f[i];
    u32 c = offsets[iter] + pp[j >> 8] + lrank[j];
    h[i] = splitmix64((u64)c + 1ull);
    out[(size_t)i * 4 + (iter + 1)] = (int)c;
}

// ---------------- fallback path (proven) ----------------

__global__ void init_iter_kernel(u64* __restrict__ keys, u32* __restrict__ vals,
                                 u64* __restrict__ nb, int n) {
    int i = blockIdx.x * blockDim.x + threadIdx.x;
    if (i < (int)TBL_SIZE) { keys[i] = EMPTY_KEY; vals[i] = 0xFFFFFFFFu; }
    if (i < n) nb[i] = 0ull;
}

__global__ void edge_kernel(const int* __restrict__ src, const int* __restrict__ dst,
                            const u64* __restrict__ h, u64* __restrict__ nb, int m) {
    int stride = gridDim.x * blockDim.x;
    for (int e = blockIdx.x * blockDim.x + threadIdx.x; e < m; e += stride) {
        atomicAdd(&nb[(u32)dst[e]], h[(u32)src[e]]);
    }
}

extern "C" void kernel_launch(void* const* d_in, const int* in_sizes, int n_in,
                              void* d_out, int out_size, void* d_ws, size_t ws_size,
                              hipStream_t stream) {
    const float* x = (const float*)d_in[0];
    const int* ei = (const int*)d_in[1];     // int32 on device
    int n = in_sizes[0] / 64;
    int m = in_sizes[1] / 2;
    const int* src = ei;
    const int* dst = ei + m;
    int* out = (int*)d_out;

    const int NPB = (n + 255) / 256;                  // rank chunks (256 each)
    const int NRB = (n + 511) / 512;                  // relabel blocks (512 each)
    const int nbuck = (n + BK_SZ - 1) >> BK_BITS;
    const size_t nstride = (size_t)nbuck << BK_BITS;  // padded node count

    auto align = [](size_t v) { return (v + 255) & ~(size_t)255; };
    size_t sz_packed = align((size_t)m * 4 + (size_t)MAXNB * 64 * 4);
    size_t sz_cnt    = align((size_t)MAXNB * NBLK * 4);
    size_t sz_bt     = align((size_t)MAXNB * 4);
    size_t sz_h      = align((size_t)n * 8);
    size_t sz_nb8    = align(nstride * 8 * NSUB);
    size_t sz_tblk   = align((size_t)TBL_SIZE * 8);
    size_t sz_tblv   = align((size_t)TBL_SIZE * 4);
    size_t sz_n4     = align((size_t)n * 4);
    size_t sz_small  = align((size_t)512 * 4);
    size_t need_fast = sz_packed + sz_cnt + 2 * sz_bt + sz_h + sz_nb8 + sz_tblk + sz_tblv
                     + 3 * sz_n4 + sz_small + 256;

    char* p = (char*)d_ws;
    bool fast = (ws_size >= need_fast) && (nbuck <= MAXNB) && ((m & 3) == 0) && (NPB <= 512);
    if (fast) {
        u32* packed  = (u32*)p; p += sz_packed;
        u32* cnt     = (u32*)p; p += sz_cnt;
        u32* total   = (u32*)p; p += sz_bt;
        u32* bases   = (u32*)p; p += sz_bt;
        u64* h       = (u64*)p; p += sz_h;
        u64* nb8     = (u64*)p; p += sz_nb8;
        u64* keys    = (u64*)p; p += sz_tblk;
        u32* vals    = (u32*)p; p += sz_tblv;
        u32* slotarr = (u32*)p; p += sz_n4;
        u32* f       = (u32*)p; p += sz_n4;
        u32* lrank   = (u32*)p; p += sz_n4;
        u32* partials= (u32*)p; p += sz_small;
        u32* offsets = (u32*)p;

        argmax_kernel<<<(n + 3) / 4, 256, 0, stream>>>(x, h, out, offsets, n);
        count_part  <<<NBLK, 1024, 0, stream>>>(dst, cnt, m, nbuck);
        scan_bucket <<<nbuck, NBLK, 0, stream>>>(cnt, total, nbuck);
        scan_bases  <<<1, 256, 0, stream>>>(total, bases, nbuck);
        scatter_part<<<NBLK, 1024, 0, stream>>>(src, dst, cnt, bases, packed, m, nbuck);

        for (int it = 0; it < 3; ++it) {
            nb_kernel    <<<nbuck * NSUB + 256, 256, 0, stream>>>(packed, bases, total, h,
                                                                  nb8, nstride, keys, vals, nbuck);
            sig_kernel8  <<<NPB, 256, 0, stream>>>(h, nb8, nstride, slotarr, keys, vals, n);
            count_rank   <<<NPB, 256, 0, stream>>>(slotarr, vals, f, lrank, partials, n);
            relabel_fused<<<NRB, 512, 0, stream>>>(f, lrank, partials, offsets, it, h, out, n, NPB);
        }
    } else {
        u64* h       = (u64*)p; p += sz_h;
        u64* nb      = (u64*)p; p += sz_h;
        u64* keys    = (u64*)p; p += sz_tblk;
        u32* vals    = (u32*)p; p += sz_tblv;
        u32* slotarr = (u32*)p; p += sz_n4;
        u32* f       = (u32*)p; p += sz_n4;
        u32* lrank   = (u32*)p; p += sz_n4;
        u32* partials= (u32*)p; p += sz_small;
        u32* offsets = (u32*)p;

        argmax_kernel<<<(n + 3) / 4, 256, 0, stream>>>(x, h, out, offsets, n);
        for (int it = 0; it < 3; ++it) {
            init_iter_kernel<<<(TBL_SIZE + 255) / 256, 256, 0, stream>>>(keys, vals, nb, n);
            edge_kernel  <<<4096, 256, 0, stream>>>(src, dst, h, nb, m);
            sig_kernel1  <<<NPB, 256, 0, stream>>>(h, nb, slotarr, keys, vals, n);
            count_rank   <<<NPB, 256, 0, stream>>>(slotarr, vals, f, lrank, partials, n);
            relabel_fused<<<NRB, 512, 0, stream>>>(f, lrank, partials, offsets, it, h, out, n, NPB);
        }
    }
}